// Round 4
// baseline (73.055 us; speedup 1.0000x reference)
//
#include <hip/hip_runtime.h>
#include <cmath>

// SE block: windowed mean-pool -> softsign(mW1+b1) -> sigmoid(softsign(hW2+b2)) -> gate x.
// B=32, M=2048, D=512, H=64, WIN=16 (M % WIN == 0, so reference edge-pad is a no-op).
// R2: NW=4 windows per block -> batched matmuls amortize the 256 KB/block weight
//     L2 traffic 4x (was ~1 GB aggregate = ~30 us of L2 BW). x re-read from warm
//     L2/L3 for gating; y stored nontemporal to keep x resident in L3.
// R3: fix compile — __builtin_nontemporal_store needs a native vector type, not float4.

constexpr int WIN = 16;
constexpr int D   = 512;
constexpr int H   = 64;
constexpr int TPB = 256;
constexpr int NW  = 4;                 // windows per block

typedef float v4f __attribute__((ext_vector_type(4)));

__global__ __launch_bounds__(TPB) void se_block_kernel(
    const float* __restrict__ x,
    const float* __restrict__ W1,
    const float* __restrict__ b1,
    const float* __restrict__ W2,
    const float* __restrict__ b2,
    float* __restrict__ y)
{
    const int tid = threadIdx.x;
    // Block handles NW consecutive windows: contiguous NW*WIN*D floats.
    const size_t base = (size_t)blockIdx.x * (size_t)(NW * WIN * D);
    const float4* __restrict__ xw = reinterpret_cast<const float4*>(x + base);
    v4f*          __restrict__ yw = reinterpret_cast<v4f*>(y + base);

    const float4* __restrict__ W1f4 = reinterpret_cast<const float4*>(W1); // [512] rows x 16 f4
    const float4* __restrict__ W2f4 = reinterpret_cast<const float4*>(W2); // [64] rows x 128 f4
    const float4* __restrict__ b2f4 = reinterpret_cast<const float4*>(b2);

    // Phase-aliased scratch: s_ps (ph1) / s_hp (ph2) / s_gp (ph3), all <= 16 KB.
    __shared__ __align__(16) char s_bufA[16 * 1024];
    __shared__ __align__(16) float s_m[NW][D];   // window means      8 KB
    __shared__ __align__(16) float s_h[NW][H];   // hidden activ.     1 KB
    __shared__ __align__(16) float s_g[NW][D];   // gates             8 KB

    float4* s_m4 = reinterpret_cast<float4*>(&s_m[0][0]);
    float4* s_h4 = reinterpret_cast<float4*>(&s_h[0][0]);
    float4* s_g4 = reinterpret_cast<float4*>(&s_g[0][0]);

    // ================= Phase 1: window means =================
    // Window w in float4 units: [w*2048, (w+1)*2048). Element i*256+tid:
    // col group c = tid&127, row = 2*i + (tid>>7).
    {
        float4* s_ps = reinterpret_cast<float4*>(s_bufA);   // [NW][256]
#pragma unroll
        for (int w = 0; w < NW; ++w) {
            float4 ps = make_float4(0.f, 0.f, 0.f, 0.f);
#pragma unroll
            for (int i = 0; i < 8; ++i) {
                const float4 v = xw[w * 2048 + i * TPB + tid];
                ps.x += v.x; ps.y += v.y; ps.z += v.z; ps.w += v.w;
            }
            s_ps[w * TPB + tid] = ps;
        }
        __syncthreads();
        // Reduce row-parity pairs -> mean. 512 tasks (NW x 128 cols) over 256 threads.
#pragma unroll
        for (int rep = 0; rep < 2; ++rep) {
            const int idx = rep * TPB + tid;          // [0,512)
            const int w  = idx >> 7;
            const int c  = idx & 127;
            const float4 a = s_ps[w * TPB + c];
            const float4 b = s_ps[w * TPB + c + 128];
            float4 m;
            const float sc = 1.0f / 16.0f;
            m.x = (a.x + b.x) * sc; m.y = (a.y + b.y) * sc;
            m.z = (a.z + b.z) * sc; m.w = (a.w + b.w) * sc;
            s_m4[w * 128 + c] = m;
        }
    }
    __syncthreads();

    // ================= Phase 2: h = softsign(m @ W1 + b1), batched over NW =================
    // Thread = (p = tid>>4 in [0,16) k-part, j4 = tid&15). k in [p*32, p*32+32).
    {
        float4* s_hp4 = reinterpret_cast<float4*>(s_bufA);  // [16][NW][16] f4 = 16 KB
        const int p  = tid >> 4;
        const int j4 = tid & 15;
        float4 acc[NW];
#pragma unroll
        for (int w = 0; w < NW; ++w) acc[w] = make_float4(0.f, 0.f, 0.f, 0.f);
#pragma unroll 2
        for (int kk4 = 0; kk4 < 8; ++kk4) {
            const int c4 = p * 8 + kk4;                 // float4 group of k
            const int k  = c4 * 4;
            const float4 w0 = W1f4[(size_t)(k + 0) * 16 + j4];
            const float4 w1 = W1f4[(size_t)(k + 1) * 16 + j4];
            const float4 w2 = W1f4[(size_t)(k + 2) * 16 + j4];
            const float4 w3 = W1f4[(size_t)(k + 3) * 16 + j4];
#pragma unroll
            for (int w = 0; w < NW; ++w) {
                const float4 mv = s_m4[w * 128 + c4];
                acc[w].x = fmaf(mv.x, w0.x, acc[w].x); acc[w].y = fmaf(mv.x, w0.y, acc[w].y);
                acc[w].z = fmaf(mv.x, w0.z, acc[w].z); acc[w].w = fmaf(mv.x, w0.w, acc[w].w);
                acc[w].x = fmaf(mv.y, w1.x, acc[w].x); acc[w].y = fmaf(mv.y, w1.y, acc[w].y);
                acc[w].z = fmaf(mv.y, w1.z, acc[w].z); acc[w].w = fmaf(mv.y, w1.w, acc[w].w);
                acc[w].x = fmaf(mv.z, w2.x, acc[w].x); acc[w].y = fmaf(mv.z, w2.y, acc[w].y);
                acc[w].z = fmaf(mv.z, w2.z, acc[w].z); acc[w].w = fmaf(mv.z, w2.w, acc[w].w);
                acc[w].x = fmaf(mv.w, w3.x, acc[w].x); acc[w].y = fmaf(mv.w, w3.y, acc[w].y);
                acc[w].z = fmaf(mv.w, w3.z, acc[w].z); acc[w].w = fmaf(mv.w, w3.w, acc[w].w);
            }
        }
#pragma unroll
        for (int w = 0; w < NW; ++w) s_hp4[(p * NW + w) * 16 + j4] = acc[w];
    }
    __syncthreads();

    // Reduce 16 k-parts, +b1, softsign. 256 threads = NW x 64.
    {
        const float* s_hp = reinterpret_cast<const float*>(s_bufA);
        const int w = tid >> 6;
        const int j = tid & 63;
        float s = b1[j];
#pragma unroll
        for (int p = 0; p < 16; ++p) s += s_hp[(p * NW + w) * 64 + j];
        s_h[w][j] = s / (1.0f + fabsf(s));
    }
    __syncthreads();

    // ================= Phase 3: g = sigmoid(softsign(h @ W2 + b2)), batched =================
    // Thread = (q = tid>>7 in {0,1} j-part, d4 = tid&127). j in [q*32, q*32+32).
    {
        float4* s_gp4 = reinterpret_cast<float4*>(s_bufA);  // [2][NW][128] f4 = 16 KB
        const int q  = tid >> 7;
        const int d4 = tid & 127;
        float4 acc[NW];
#pragma unroll
        for (int w = 0; w < NW; ++w) acc[w] = make_float4(0.f, 0.f, 0.f, 0.f);
#pragma unroll 2
        for (int jj4 = 0; jj4 < 8; ++jj4) {
            const int jg = q * 8 + jj4;                 // float4 group of j
            const int j  = jg * 4;
            const float4 w0 = W2f4[(size_t)(j + 0) * 128 + d4];
            const float4 w1 = W2f4[(size_t)(j + 1) * 128 + d4];
            const float4 w2 = W2f4[(size_t)(j + 2) * 128 + d4];
            const float4 w3 = W2f4[(size_t)(j + 3) * 128 + d4];
#pragma unroll
            for (int w = 0; w < NW; ++w) {
                const float4 hv = s_h4[w * 16 + jg];
                acc[w].x = fmaf(hv.x, w0.x, acc[w].x); acc[w].y = fmaf(hv.x, w0.y, acc[w].y);
                acc[w].z = fmaf(hv.x, w0.z, acc[w].z); acc[w].w = fmaf(hv.x, w0.w, acc[w].w);
                acc[w].x = fmaf(hv.y, w1.x, acc[w].x); acc[w].y = fmaf(hv.y, w1.y, acc[w].y);
                acc[w].z = fmaf(hv.y, w1.z, acc[w].z); acc[w].w = fmaf(hv.y, w1.w, acc[w].w);
                acc[w].x = fmaf(hv.z, w2.x, acc[w].x); acc[w].y = fmaf(hv.z, w2.y, acc[w].y);
                acc[w].z = fmaf(hv.z, w2.z, acc[w].z); acc[w].w = fmaf(hv.z, w2.w, acc[w].w);
                acc[w].x = fmaf(hv.w, w3.x, acc[w].x); acc[w].y = fmaf(hv.w, w3.y, acc[w].y);
                acc[w].z = fmaf(hv.w, w3.z, acc[w].z); acc[w].w = fmaf(hv.w, w3.w, acc[w].w);
            }
        }
#pragma unroll
        for (int w = 0; w < NW; ++w) s_gp4[(q * NW + w) * 128 + d4] = acc[w];
    }
    __syncthreads();

    // Reduce 2 j-parts, +b2, softsign, sigmoid. 512 float4 tasks over 256 threads.
    {
        const float4* s_gp4 = reinterpret_cast<const float4*>(s_bufA);
#pragma unroll
        for (int rep = 0; rep < 2; ++rep) {
            const int idx = rep * TPB + tid;           // [0,512) over [NW][128]
            const int w  = idx >> 7;
            const int d4 = idx & 127;
            const float4 a = s_gp4[(0 * NW + w) * 128 + d4];
            const float4 b = s_gp4[(1 * NW + w) * 128 + d4];
            const float4 bb = b2f4[d4];
            float4 s;
            s.x = a.x + b.x + bb.x; s.y = a.y + b.y + bb.y;
            s.z = a.z + b.z + bb.z; s.w = a.w + b.w + bb.w;
            s.x = s.x / (1.0f + fabsf(s.x)); s.y = s.y / (1.0f + fabsf(s.y));
            s.z = s.z / (1.0f + fabsf(s.z)); s.w = s.w / (1.0f + fabsf(s.w));
            float4 g;
            g.x = 1.0f / (1.0f + __expf(-s.x)); g.y = 1.0f / (1.0f + __expf(-s.y));
            g.z = 1.0f / (1.0f + __expf(-s.z)); g.w = 1.0f / (1.0f + __expf(-s.w));
            s_g4[w * 128 + d4] = g;
        }
    }
    __syncthreads();

    // ================= Phase 4: re-read x (L2/L3-warm), gate, store =================
    {
        const int c = tid & 127;
#pragma unroll
        for (int w = 0; w < NW; ++w) {
            const float4 g = s_g4[w * 128 + c];
#pragma unroll
            for (int i = 0; i < 8; ++i) {
                const float4 v = xw[w * 2048 + i * TPB + tid];
                v4f o;
                o.x = v.x * g.x; o.y = v.y * g.y; o.z = v.z * g.z; o.w = v.w * g.w;
                __builtin_nontemporal_store(o, &yw[w * 2048 + i * TPB + tid]);
            }
        }
    }
}

extern "C" void kernel_launch(void* const* d_in, const int* in_sizes, int n_in,
                              void* d_out, int out_size, void* d_ws, size_t ws_size,
                              hipStream_t stream) {
    const float* x  = (const float*)d_in[0];
    const float* W1 = (const float*)d_in[1];
    const float* b1 = (const float*)d_in[2];
    const float* W2 = (const float*)d_in[3];
    const float* b2 = (const float*)d_in[4];
    float* y = (float*)d_out;

    const int n_windows = in_sizes[0] / (WIN * D);   // B * (M/WIN) = 4096
    const int n_blocks  = n_windows / NW;            // 1024
    se_block_kernel<<<dim3(n_blocks), dim3(TPB), 0, stream>>>(x, W1, b1, W2, b2, y);
}

// Round 5
// 56.431 us; speedup vs baseline: 1.2946x; 1.2946x over previous
//
#include <hip/hip_runtime.h>
#include <cmath>

// SE block: windowed mean-pool -> softsign(mW1+b1) -> sigmoid(softsign(hW2+b2)) -> gate x.
// B=32, M=2048, D=512, H=64, WIN=16 (M % WIN == 0, so reference edge-pad is a no-op).
// R4: x in registers (single HBM read of x, like R1/R2) + NW=2 windows per block
//     (halves the ~1 GB aggregate weight L2 traffic; each weight load feeds 2x FMAs).
//     Regular stores (R3's nontemporal stores lost the L3 x-carryover: FETCH 67->133 MB).

constexpr int WIN = 16;
constexpr int D   = 512;
constexpr int H   = 64;
constexpr int TPB = 256;
constexpr int NW  = 2;                 // windows per block

__global__ __launch_bounds__(TPB, 4) void se_block_kernel(
    const float* __restrict__ x,
    const float* __restrict__ W1,
    const float* __restrict__ b1,
    const float* __restrict__ W2,
    const float* __restrict__ b2,
    float* __restrict__ y)
{
    const int tid = threadIdx.x;
    // Block handles NW consecutive windows: contiguous NW*WIN*D floats.
    const size_t base = (size_t)blockIdx.x * (size_t)(NW * WIN * D);
    const float4* __restrict__ xw = reinterpret_cast<const float4*>(x + base);
    float4*       __restrict__ yw = reinterpret_cast<float4*>(y + base);

    const float4* __restrict__ W1f4 = reinterpret_cast<const float4*>(W1); // [512] rows x 16 f4
    const float4* __restrict__ W2f4 = reinterpret_cast<const float4*>(W2); // [64] rows x 128 f4
    const float4* __restrict__ b2f4 = reinterpret_cast<const float4*>(b2);

    __shared__ float4 s_ps[NW][TPB];        // per-thread partial sums          8 KB
    __shared__ float4 s_m4[NW][D / 4];      // window means                     4 KB
    __shared__ float4 s_hp[16][NW][H / 4];  // matmul1 partials (16 k-parts)    8 KB
    __shared__ float  s_h[NW][H];           // hidden activations               512 B
    __shared__ float4 s_gp[2][NW][D / 4];   // matmul2 partials (2 j-parts)     8 KB
    __shared__ float4 s_g4[NW][D / 4];      // gates                            4 KB

    // ---- Load x into registers. Window w, float4 element i*256+tid:
    //      col group c = tid&127, row = 2*i + (tid>>7).
    float4 r[NW][8];
#pragma unroll
    for (int w = 0; w < NW; ++w)
#pragma unroll
        for (int i = 0; i < 8; ++i) r[w][i] = xw[w * 2048 + i * TPB + tid];

    // ================= Phase 1: window means =================
#pragma unroll
    for (int w = 0; w < NW; ++w) {
        float4 ps = r[w][0];
#pragma unroll
        for (int i = 1; i < 8; ++i) {
            ps.x += r[w][i].x; ps.y += r[w][i].y; ps.z += r[w][i].z; ps.w += r[w][i].w;
        }
        s_ps[w][tid] = ps;
    }
    __syncthreads();
    {   // 256 tasks = NW x 128 col-groups
        const int w = tid >> 7;
        const int c = tid & 127;
        const float4 a = s_ps[w][c];
        const float4 b = s_ps[w][c + 128];
        const float sc = 1.0f / 16.0f;
        float4 m;
        m.x = (a.x + b.x) * sc; m.y = (a.y + b.y) * sc;
        m.z = (a.z + b.z) * sc; m.w = (a.w + b.w) * sc;
        s_m4[w][c] = m;
    }
    __syncthreads();

    // ================= Phase 2: h = softsign(m @ W1 + b1), batched over NW =================
    // Thread = (p = tid>>4 k-part, j4 = tid&15). k in [p*32, p*32+32).
    {
        const int p  = tid >> 4;
        const int j4 = tid & 15;
        float4 acc[NW];
#pragma unroll
        for (int w = 0; w < NW; ++w) acc[w] = make_float4(0.f, 0.f, 0.f, 0.f);
#pragma unroll 2
        for (int kk4 = 0; kk4 < 8; ++kk4) {
            const int c4 = p * 8 + kk4;                 // float4 group of k
            const int k  = c4 * 4;
            const float4 w0 = W1f4[(size_t)(k + 0) * 16 + j4];
            const float4 w1 = W1f4[(size_t)(k + 1) * 16 + j4];
            const float4 w2 = W1f4[(size_t)(k + 2) * 16 + j4];
            const float4 w3 = W1f4[(size_t)(k + 3) * 16 + j4];
#pragma unroll
            for (int w = 0; w < NW; ++w) {
                const float4 mv = s_m4[w][c4];
                acc[w].x = fmaf(mv.x, w0.x, acc[w].x); acc[w].y = fmaf(mv.x, w0.y, acc[w].y);
                acc[w].z = fmaf(mv.x, w0.z, acc[w].z); acc[w].w = fmaf(mv.x, w0.w, acc[w].w);
                acc[w].x = fmaf(mv.y, w1.x, acc[w].x); acc[w].y = fmaf(mv.y, w1.y, acc[w].y);
                acc[w].z = fmaf(mv.y, w1.z, acc[w].z); acc[w].w = fmaf(mv.y, w1.w, acc[w].w);
                acc[w].x = fmaf(mv.z, w2.x, acc[w].x); acc[w].y = fmaf(mv.z, w2.y, acc[w].y);
                acc[w].z = fmaf(mv.z, w2.z, acc[w].z); acc[w].w = fmaf(mv.z, w2.w, acc[w].w);
                acc[w].x = fmaf(mv.w, w3.x, acc[w].x); acc[w].y = fmaf(mv.w, w3.y, acc[w].y);
                acc[w].z = fmaf(mv.w, w3.z, acc[w].z); acc[w].w = fmaf(mv.w, w3.w, acc[w].w);
            }
        }
#pragma unroll
        for (int w = 0; w < NW; ++w) s_hp[p][w][j4] = acc[w];
    }
    __syncthreads();

    // Reduce 16 k-parts, +b1, softsign. NW*64 = 128 tasks.
    if (tid < NW * H) {
        const float* s_hpf = reinterpret_cast<const float*>(s_hp);
        const int w = tid >> 6;
        const int j = tid & 63;
        float s = b1[j];
#pragma unroll
        for (int p = 0; p < 16; ++p) s += s_hpf[(p * NW + w) * H + j];
        s_h[w][j] = s / (1.0f + fabsf(s));
    }
    __syncthreads();

    // ================= Phase 3: g = sigmoid(softsign(h @ W2 + b2)), batched =================
    // Thread = (q = tid>>7 j-part, d4 = tid&127). j in [q*32, q*32+32).
    {
        const float4* s_h4 = reinterpret_cast<const float4*>(&s_h[0][0]); // [NW][16]
        const int q  = tid >> 7;
        const int d4 = tid & 127;
        float4 acc[NW];
#pragma unroll
        for (int w = 0; w < NW; ++w) acc[w] = make_float4(0.f, 0.f, 0.f, 0.f);
#pragma unroll 2
        for (int jj4 = 0; jj4 < 8; ++jj4) {
            const int jg = q * 8 + jj4;                 // float4 group of j
            const int j  = jg * 4;
            const float4 w0 = W2f4[(size_t)(j + 0) * 128 + d4];
            const float4 w1 = W2f4[(size_t)(j + 1) * 128 + d4];
            const float4 w2 = W2f4[(size_t)(j + 2) * 128 + d4];
            const float4 w3 = W2f4[(size_t)(j + 3) * 128 + d4];
#pragma unroll
            for (int w = 0; w < NW; ++w) {
                const float4 hv = s_h4[w * 16 + jg];
                acc[w].x = fmaf(hv.x, w0.x, acc[w].x); acc[w].y = fmaf(hv.x, w0.y, acc[w].y);
                acc[w].z = fmaf(hv.x, w0.z, acc[w].z); acc[w].w = fmaf(hv.x, w0.w, acc[w].w);
                acc[w].x = fmaf(hv.y, w1.x, acc[w].x); acc[w].y = fmaf(hv.y, w1.y, acc[w].y);
                acc[w].z = fmaf(hv.y, w1.z, acc[w].z); acc[w].w = fmaf(hv.y, w1.w, acc[w].w);
                acc[w].x = fmaf(hv.z, w2.x, acc[w].x); acc[w].y = fmaf(hv.z, w2.y, acc[w].y);
                acc[w].z = fmaf(hv.z, w2.z, acc[w].z); acc[w].w = fmaf(hv.z, w2.w, acc[w].w);
                acc[w].x = fmaf(hv.w, w3.x, acc[w].x); acc[w].y = fmaf(hv.w, w3.y, acc[w].y);
                acc[w].z = fmaf(hv.w, w3.z, acc[w].z); acc[w].w = fmaf(hv.w, w3.w, acc[w].w);
            }
        }
#pragma unroll
        for (int w = 0; w < NW; ++w) s_gp[q][w][d4] = acc[w];
    }
    __syncthreads();

    // Reduce 2 j-parts, +b2, softsign, sigmoid. 256 tasks = NW x 128.
    {
        const int w  = tid >> 7;
        const int d4 = tid & 127;
        const float4 a  = s_gp[0][w][d4];
        const float4 b  = s_gp[1][w][d4];
        const float4 bb = b2f4[d4];
        float4 s;
        s.x = a.x + b.x + bb.x; s.y = a.y + b.y + bb.y;
        s.z = a.z + b.z + bb.z; s.w = a.w + b.w + bb.w;
        s.x = s.x / (1.0f + fabsf(s.x)); s.y = s.y / (1.0f + fabsf(s.y));
        s.z = s.z / (1.0f + fabsf(s.z)); s.w = s.w / (1.0f + fabsf(s.w));
        float4 g;
        g.x = 1.0f / (1.0f + __expf(-s.x)); g.y = 1.0f / (1.0f + __expf(-s.y));
        g.z = 1.0f / (1.0f + __expf(-s.z)); g.w = 1.0f / (1.0f + __expf(-s.w));
        s_g4[w][d4] = g;
    }
    __syncthreads();

    // ================= Phase 4: gate from registers, store =================
    {
        const int c = tid & 127;
#pragma unroll
        for (int w = 0; w < NW; ++w) {
            const float4 g = s_g4[w][c];
#pragma unroll
            for (int i = 0; i < 8; ++i) {
                float4 o;
                o.x = r[w][i].x * g.x; o.y = r[w][i].y * g.y;
                o.z = r[w][i].z * g.z; o.w = r[w][i].w * g.w;
                yw[w * 2048 + i * TPB + tid] = o;
            }
        }
    }
}

extern "C" void kernel_launch(void* const* d_in, const int* in_sizes, int n_in,
                              void* d_out, int out_size, void* d_ws, size_t ws_size,
                              hipStream_t stream) {
    const float* x  = (const float*)d_in[0];
    const float* W1 = (const float*)d_in[1];
    const float* b1 = (const float*)d_in[2];
    const float* W2 = (const float*)d_in[3];
    const float* b2 = (const float*)d_in[4];
    float* y = (float*)d_out;

    const int n_windows = in_sizes[0] / (WIN * D);   // B * (M/WIN) = 4096
    const int n_blocks  = n_windows / NW;            // 2048
    se_block_kernel<<<dim3(n_blocks), dim3(TPB), 0, stream>>>(x, W1, b1, W2, b2, y);
}